// Round 3
// baseline (349.609 us; speedup 1.0000x reference)
//
#include <hip/hip_runtime.h>
#include <stdint.h>
#include <stddef.h>

#define B_ 8
#define S_ 2048
#define D_ 512

typedef __attribute__((ext_vector_type(8))) short short8;   // 8 x bf16 MFMA frag
typedef __attribute__((ext_vector_type(4))) float f32x4;    // MFMA accum

// ---- dynamic LDS layout (bytes); all regions dedicated, no aliasing ----
#define LDS_BYTES 156416
#define OFF_K   0         // 64 keys x 1024B bf16 K tile, chunk-swizzled
#define OFF_V   65536     // FAST: 4 waves x [128 dv][128B] V^T; SLOW: V natural [64 key][1024B]
#define OFF_ST  131072    // S^T fp32 [64 key][256B], xblk-swizzled
#define OFF_P   147456    // P bf16 [64 q][128B], chunk-swizzled
#define OFF_A   155648    // 64 f32 alpha
#define OFF_L   155904    // 64 f32 l
#define OFF_M   156160    // 64 u32 packed mask bits for this batch

__device__ __forceinline__ void gl_lds16(const void* g, void* l) {
  __builtin_amdgcn_global_load_lds(
      (const __attribute__((address_space(1))) uint32_t*)g,
      (__attribute__((address_space(3))) uint32_t*)l, 16, 0, 0);
}

__device__ __forceinline__ uint32_t f2bf(float f) {
  union { float f; uint32_t u; } x; x.f = f;
  uint32_t r = x.u + 0x7FFFu + ((x.u >> 16) & 1u);  // RNE, finite inputs only
  return r >> 16;
}

// fp32 N(0,1) data: exponent field in [~90,130]; packed-bf16 N(0,1) read as u32
// has field = bits14..7 of the high bf16 -> ~200..253. Uniform across block.
__device__ __forceinline__ bool sniff_fp32(const void* p) {
  const uint32_t* w = (const uint32_t*)p;
  bool ok = true;
  #pragma unroll 1
  for (int i = 0; i < 64; ++i) {
    uint32_t e = (w[i] >> 23) & 0xFFu;
    if (!(e == 0u || (e >= 64u && e <= 192u))) ok = false;
  }
  return ok;
}

__device__ __forceinline__ short8 cvt8(const void* src, bool fp32) {
  short8 d;
  if (fp32) {
    const float* s = (const float*)src;
    f32x4 a = *(const f32x4*)s, c = *(const f32x4*)(s + 4);
    #pragma unroll
    for (int j = 0; j < 4; ++j) { d[j] = (short)f2bf(a[j]); d[4 + j] = (short)f2bf(c[j]); }
  } else {
    d = *(const short8*)src;
  }
  return d;
}

// ---------- K (any dtype) -> bf16, same layout ----------
__global__ void kbf_kernel(const void* __restrict__ in, uint16_t* __restrict__ out) {
  bool fp32 = sniff_fp32(in);
  size_t i = ((size_t)blockIdx.x * 256 + threadIdx.x) * 8;
  const void* src = fp32 ? (const void*)((const float*)in + i)
                         : (const void*)((const uint16_t*)in + i);
  *(short8*)(out + i) = cvt8(src, fp32);
}

// ---------- V [b][key][dv] (any dtype) -> V^T [b][dv][key] bf16 ----------
__global__ void vt_kernel(const void* __restrict__ V, uint16_t* __restrict__ vt) {
  __shared__ uint16_t tile[64][72];
  bool fp32 = sniff_fp32(V);
  int kt = blockIdx.x, dt = blockIdx.y, b = blockIdx.z;
  int t = threadIdx.x;
  size_t base = ((size_t)b * S_ + (size_t)kt * 64) * D_ + dt * 64;
  #pragma unroll
  for (int p = 0; p < 2; ++p) {
    int row = p * 32 + (t >> 3);
    int c8  = (t & 7) * 8;
    size_t off = base + (size_t)row * D_ + c8;
    const void* src = fp32 ? (const void*)((const float*)V + off)
                           : (const void*)((const uint16_t*)V + off);
    *(short8*)(&tile[row][c8]) = cvt8(src, fp32);
  }
  __syncthreads();
  uint16_t* dst = vt + ((size_t)b * D_ + dt * 64) * S_ + (size_t)kt * 64;
  #pragma unroll
  for (int p = 0; p < 2; ++p) {
    int idx = p * 256 + t;
    int dvr = idx >> 3;
    int kc  = idx & 7;
    short8 o;
    #pragma unroll
    for (int j = 0; j < 8; ++j) o[j] = (short)tile[kc * 8 + j][dvr];
    *(short8*)(dst + (size_t)dvr * S_ + kc * 8) = o;
  }
}

// ---------- staging (FAST: bf16 ws buffers via global_load_lds) ----------
__device__ __forceinline__ void stage_K(char* smem, const uint16_t* kg, int w, int lane, int kt) {
  #pragma unroll
  for (int p = 0; p < 16; ++p) {
    int n = p * 4 + w;
    int g = (lane & ~7) | ((lane ^ n) & 7);          // slot s holds chunk (s&~7)|((s^n)&7)
    gl_lds16(kg + ((size_t)(kt * 64 + n)) * D_ + g * 8, smem + OFF_K + p * 4096 + w * 1024);
  }
}
__device__ __forceinline__ void stage_VT(char* smem, const uint16_t* vtg, int w, int lane, int kt) {
  #pragma unroll
  for (int p = 0; p < 16; ++p) {
    int dvl = p * 8 + (lane >> 3);                   // wave-local dv row [0,128)
    int g = (lane & 7) ^ (dvl & 7);                  // slot s holds chunk s^(dvl&7)
    gl_lds16(vtg + ((size_t)(w * 128 + dvl)) * S_ + kt * 64 + g * 8,
             smem + OFF_V + w * 16384 + p * 1024);
  }
}
// ---------- staging (SLOW: convert through registers) ----------
__device__ __forceinline__ void stage_K_slow(char* smem, const void* kg, bool fp32,
                                             int w, int lane, int kt) {
  #pragma unroll
  for (int p = 0; p < 16; ++p) {
    int n = p * 4 + w;
    size_t off = ((size_t)(kt * 64 + n)) * D_ + lane * 8;
    const void* src = fp32 ? (const void*)((const float*)kg + off)
                           : (const void*)((const uint16_t*)kg + off);
    short8 d = cvt8(src, fp32);
    int s = (lane & ~7) | ((lane ^ n) & 7);
    *(short8*)(smem + OFF_K + n * 1024 + s * 16) = d;
  }
}
__device__ __forceinline__ void stage_V_slow(char* smem, const void* vg, bool fp32,
                                             int w, int lane, int kt) {
  #pragma unroll
  for (int p = 0; p < 16; ++p) {
    int n = p * 4 + w;
    size_t off = ((size_t)(kt * 64 + n)) * D_ + lane * 8;
    const void* src = fp32 ? (const void*)((const float*)vg + off)
                           : (const void*)((const uint16_t*)vg + off);
    short8 d = cvt8(src, fp32);
    *(short8*)(smem + OFF_V + n * 1024 + lane * 16) = d;   // natural layout
  }
}

// ---------- flash attention: 64-query tile per block, 4 waves ----------
template<bool FAST>
__global__ __launch_bounds__(256, 1)
void attn_kernel(const void* __restrict__ Q, const void* __restrict__ K,
                 const void* __restrict__ V, const void* __restrict__ mask,
                 const uint16_t* __restrict__ kbf, const uint16_t* __restrict__ vtbf,
                 void* __restrict__ out) {
  extern __shared__ char smem[];
  const int tid  = threadIdx.x;
  const int lane = tid & 63;
  const int w    = tid >> 6;
  const int m15  = lane & 15;
  const int kq   = lane >> 4;

  const bool fp32 = sniff_fp32(Q);

  const int b     = blockIdx.x;       // batch; blockId%8 == XCD for L2 locality
  const int qbase = blockIdx.y * 64;
  const int rbase = (w >> 1) * 32;    // QK^T quadrant rows (q)
  const int cbase = (w & 1) * 32;     // QK^T quadrant cols (keys)

  const uint16_t* kgf  = FAST ? (kbf + (size_t)b * S_ * D_) : nullptr;
  const uint16_t* vtgf = FAST ? (vtbf + (size_t)b * D_ * S_) : nullptr;
  const void* kgs = fp32 ? (const void*)((const float*)K + (size_t)b * S_ * D_)
                         : (const void*)((const uint16_t*)K + (size_t)b * S_ * D_);
  const void* vgs = fp32 ? (const void*)((const float*)V + (size_t)b * S_ * D_)
                         : (const void*)((const uint16_t*)V + (size_t)b * S_ * D_);

  // ---- pack this batch's key mask into 64 LDS words (dtype auto-detect) ----
  if (tid < 64) {
    const uint32_t* mw = (const uint32_t*)mask;
    const uint8_t*  mb = (const uint8_t*)mask;
    bool is64 = true, any_even = false, is32 = true;
    for (int j = 0; j < 64; ++j) {
      uint32_t lo = mw[2 * j], hi = mw[2 * j + 1];
      if (hi != 0u || lo > 1u) is64 = false;
      if (lo) any_even = true;
    }
    is64 = is64 && any_even;
    for (int j = 0; j < 128; ++j) {
      uint32_t x = mw[j];
      if (x != 0u && x != 1u && x != 0x3F800000u) is32 = false;
    }
    uint32_t bits = 0;
    int base = b * S_ + tid * 32;
    for (int e = 0; e < 32; ++e) {
      uint32_t x = is64 ? mw[2 * (base + e)]
                        : (is32 ? mw[base + e] : (uint32_t)mb[base + e]);
      bits |= (x ? 1u : 0u) << e;
    }
    *(uint32_t*)(smem + OFF_M + tid * 4) = bits;
  }

  // ---- Q fragments resident in registers (row-major == A-layout) ----
  short8 aq[2][16];
  {
    size_t q0 = ((size_t)b * S_ + qbase + rbase + m15) * D_ + kq * 8;
    #pragma unroll
    for (int rt = 0; rt < 2; ++rt)
      #pragma unroll
      for (int sl = 0; sl < 16; ++sl) {
        size_t off = q0 + (size_t)rt * 16 * D_ + sl * 32;
        const void* src = fp32 ? (const void*)((const float*)Q + off)
                               : (const void*)((const uint16_t*)Q + off);
        aq[rt][sl] = cvt8(src, fp32);
      }
  }

  f32x4 acc_o[4][8];
  #pragma unroll
  for (int i = 0; i < 4; ++i)
    #pragma unroll
    for (int j = 0; j < 8; ++j)
      acc_o[i][j] = (f32x4){0.f, 0.f, 0.f, 0.f};

  float m_run = -1e30f, l_run = 0.f;
  const float k1 = 0.06375872f;       // log2(e)/sqrt(512); exp2-domain softmax

  if (FAST) { stage_K(smem, kgf, w, lane, 0); stage_VT(smem, vtgf, w, lane, 0); }

  for (int kt = 0; kt < 32; ++kt) {
    if (!FAST) {
      __syncthreads();                          // prior-iter LDS reads drained
      stage_K_slow(smem, kgs, fp32, w, lane, kt);
      stage_V_slow(smem, vgs, fp32, w, lane, kt);
    }
    __syncthreads();                            // B1: staging landed (vmcnt0 before barrier)

    int key0 = kt * 64 + cbase + m15, key1 = key0 + 16;
    float bv0 = ((*(const uint32_t*)(smem + OFF_M + (key0 >> 5) * 4) >> (key0 & 31)) & 1u)
                ? -3.0e38f : 0.f;
    float bv1 = ((*(const uint32_t*)(smem + OFF_M + (key1 >> 5) * 4) >> (key1 & 31)) & 1u)
                ? -3.0e38f : 0.f;

    // ---- QK^T: Q from registers, K B-frags from LDS ----
    f32x4 acc_s[2][2];
    #pragma unroll
    for (int i = 0; i < 2; ++i)
      #pragma unroll
      for (int j = 0; j < 2; ++j)
        acc_s[i][j] = (f32x4){0.f, 0.f, 0.f, 0.f};
    #pragma unroll
    for (int sl = 0; sl < 16; ++sl) {
      short8 bf[2];
      #pragma unroll
      for (int ct = 0; ct < 2; ++ct) {
        int n  = cbase + ct * 16 + m15;
        int c  = sl * 4 + kq;
        int cs = (c & ~7) | ((c ^ n) & 7);
        bf[ct] = *(const short8*)(smem + OFF_K + n * 1024 + cs * 16);
      }
      #pragma unroll
      for (int rt = 0; rt < 2; ++rt)
        #pragma unroll
        for (int ct = 0; ct < 2; ++ct)
          acc_s[rt][ct] = __builtin_amdgcn_mfma_f32_16x16x32_bf16(
              aq[rt][sl], bf[ct], acc_s[rt][ct], 0, 0, 0);
    }

    // ---- S^T fp32 (exp2-domain, bias folded), xblk-swizzled ----
    #pragma unroll
    for (int rt = 0; rt < 2; ++rt) {
      int q0  = rbase + rt * 16 + kq * 4;
      int blk = q0 >> 2;
      #pragma unroll
      for (int ct = 0; ct < 2; ++ct) {
        int key  = cbase + ct * 16 + m15;
        int xblk = blk ^ (key & 7) ^ (((key >> 4) & 3) << 2);
        float bvv = ct ? bv1 : bv0;
        f32x4 sv;
        #pragma unroll
        for (int r = 0; r < 4; ++r) sv[r] = acc_s[rt][ct][r] * k1 + bvv;
        *(f32x4*)(smem + OFF_ST + key * 256 + xblk * 16) = sv;
      }
    }
    __syncthreads();                            // B2: S^T visible, K reads drained

    // ---- online softmax: wave w owns q rows [w*16, w*16+16) ----
    {
      int row = w * 16 + m15;
      float u[16];
      #pragma unroll
      for (int j = 0; j < 16; ++j) {
        int key  = kq * 16 + j;
        int xblk = (row >> 2) ^ (key & 7) ^ (((key >> 4) & 3) << 2);
        u[j] = *(const float*)(smem + OFF_ST + key * 256 + xblk * 16 + (row & 3) * 4);
      }
      float mt = u[0];
      #pragma unroll
      for (int j = 1; j < 16; ++j) mt = fmaxf(mt, u[j]);
      mt = fmaxf(mt, __shfl_xor(mt, 16, 64));
      mt = fmaxf(mt, __shfl_xor(mt, 32, 64));
      float m_new = fmaxf(m_run, mt);
      float alpha = exp2f(m_run - m_new);
      float s = 0.f;
      #pragma unroll
      for (int j = 0; j < 16; ++j) { u[j] = exp2f(u[j] - m_new); s += u[j]; }
      s += __shfl_xor(s, 16, 64);
      s += __shfl_xor(s, 32, 64);
      l_run = l_run * alpha + s;
      m_run = m_new;
      #pragma unroll
      for (int hf = 0; hf < 2; ++hf) {
        uint32_t d[4];
        #pragma unroll
        for (int q = 0; q < 4; ++q)
          d[q] = f2bf(u[hf * 8 + q * 2]) | (f2bf(u[hf * 8 + q * 2 + 1]) << 16);
        int c  = kq * 2 + hf;
        int cs = c ^ (row & 7);
        *(uint4*)(smem + OFF_P + row * 128 + cs * 16) = make_uint4(d[0], d[1], d[2], d[3]);
      }
      if (kq == 0) {
        *(float*)(smem + OFF_A + row * 4) = alpha;
        *(float*)(smem + OFF_L + row * 4) = l_run;
      }
    }
    __syncthreads();                            // B3: P/alpha/l visible

    if (FAST && kt < 31) stage_K(smem, kgf, w, lane, kt + 1);   // DMA overlaps PV

    // ---- PV: wave w owns dv slice [w*128, w*128+128) ----
    #pragma unroll
    for (int rt = 0; rt < 4; ++rt) {
      f32x4 al = *(const f32x4*)(smem + OFF_A + (rt * 16 + kq * 4) * 4);
      #pragma unroll
      for (int ct = 0; ct < 8; ++ct) acc_o[rt][ct] *= al;
    }
    short8 ap[4][2];
    #pragma unroll
    for (int rt = 0; rt < 4; ++rt)
      #pragma unroll
      for (int ks = 0; ks < 2; ++ks) {
        int qq = rt * 16 + m15;
        int cs = (ks * 4 + kq) ^ (qq & 7);
        ap[rt][ks] = *(const short8*)(smem + OFF_P + qq * 128 + cs * 16);
      }
    #pragma unroll
    for (int ks = 0; ks < 2; ++ks)
      #pragma unroll
      for (int ct = 0; ct < 8; ++ct) {
        short8 bv;
        if (FAST) {
          int dvl = ct * 16 + m15;
          int cs  = (ks * 4 + kq) ^ (dvl & 7);
          bv = *(const short8*)(smem + OFF_V + w * 16384 + dvl * 128 + cs * 16);
        } else {
          #pragma unroll
          for (int j = 0; j < 8; ++j)
            bv[j] = *(const short*)(smem + OFF_V + (ks * 32 + kq * 8 + j) * 1024
                                    + (w * 128 + ct * 16 + m15) * 2);
        }
        #pragma unroll
        for (int rt = 0; rt < 4; ++rt)
          acc_o[rt][ct] = __builtin_amdgcn_mfma_f32_16x16x32_bf16(
              ap[rt][ks], bv, acc_o[rt][ct], 0, 0, 0);
      }

    if (FAST && kt < 31) stage_VT(smem, vtgf, w, lane, kt + 1); // wave-private region
  }

  // ---- epilogue: O /= l (guarded), store in input dtype ----
  #pragma unroll
  for (int rt = 0; rt < 4; ++rt) {
    f32x4 lv = *(const f32x4*)(smem + OFF_L + (rt * 16 + kq * 4) * 4);
    f32x4 inv;
    #pragma unroll
    for (int r = 0; r < 4; ++r) inv[r] = lv[r] > 0.f ? 1.f / lv[r] : 0.f;
    #pragma unroll
    for (int ct = 0; ct < 8; ++ct) {
      int col = w * 128 + ct * 16 + m15;
      #pragma unroll
      for (int r = 0; r < 4; ++r) {
        int row = qbase + rt * 16 + kq * 4 + r;
        size_t idx = ((size_t)b * S_ + row) * D_ + col;
        float val = acc_o[rt][ct][r] * inv[r];
        if (fp32) ((float*)out)[idx] = val;
        else      ((uint16_t*)out)[idx] = (uint16_t)f2bf(val);
      }
    }
  }
}

extern "C" void kernel_launch(void* const* d_in, const int* in_sizes, int n_in,
                              void* d_out, int out_size, void* d_ws, size_t ws_size,
                              hipStream_t stream) {
  (void)in_sizes; (void)n_in; (void)out_size;
  const void* Q    = d_in[0];
  const void* K    = d_in[1];
  const void* V    = d_in[2];
  const void* mask = d_in[3];

  const size_t half = (size_t)B_ * S_ * D_ * 2;     // 16 MiB per bf16 buffer
  bool fast = ws_size >= 2 * half;

  if (fast) {
    uint16_t* kbf  = (uint16_t*)d_ws;
    uint16_t* vtbf = (uint16_t*)((char*)d_ws + half);
    kbf_kernel<<<4096, 256, 0, stream>>>(K, kbf);
    vt_kernel<<<dim3(32, 8, 8), 256, 0, stream>>>(V, vtbf);
    hipFuncSetAttribute((const void*)attn_kernel<true>,
                        hipFuncAttributeMaxDynamicSharedMemorySize, LDS_BYTES);
    attn_kernel<true><<<dim3(8, 32), 256, LDS_BYTES, stream>>>(
        Q, K, V, mask, kbf, vtbf, d_out);
  } else {
    hipFuncSetAttribute((const void*)attn_kernel<false>,
                        hipFuncAttributeMaxDynamicSharedMemorySize, LDS_BYTES);
    attn_kernel<false><<<dim3(8, 32), 256, LDS_BYTES, stream>>>(
        Q, K, V, mask, nullptr, nullptr, d_out);
  }
}

// Round 4
// 338.495 us; speedup vs baseline: 1.0328x; 1.0328x over previous
//
#include <hip/hip_runtime.h>
#include <stdint.h>
#include <stddef.h>

#define B_ 8
#define S_ 2048
#define D_ 512
#define QT 32            // q rows per block
#define KTL 32           // keys per iter
#define NIT (S_ / KTL)   // 64

typedef __attribute__((ext_vector_type(8))) short short8;   // 8 x bf16 MFMA frag
typedef __attribute__((ext_vector_type(4))) float f32x4;    // MFMA accum

// ---- LDS layout (bytes); 72192 per block -> 2 blocks/CU (144 KiB of 160) ----
#define OFF_K   0         // 32 keys x 1024B bf16, chunk-swizzled
#define OFF_V   32768     // FAST: 4 waves x [128 dv][64B keys]; SLOW: V natural [32 key][1024B]
#define OFF_ST  65536     // S^T fp32 [32 key][128B], xblk-swizzled
#define OFF_P   69632     // P bf16 [32 q][64B]
#define OFF_A   71680     // 32 f32 alpha
#define OFF_L   71808     // 32 f32 l
#define OFF_M   71936     // 64 u32 packed mask bits for this batch
#define LDS_BYTES 72192

__device__ __forceinline__ void gl_lds16(const void* g, void* l) {
  __builtin_amdgcn_global_load_lds(
      (const __attribute__((address_space(1))) uint32_t*)g,
      (__attribute__((address_space(3))) uint32_t*)l, 16, 0, 0);
}

__device__ __forceinline__ uint32_t f2bf(float f) {
  union { float f; uint32_t u; } x; x.f = f;
  uint32_t r = x.u + 0x7FFFu + ((x.u >> 16) & 1u);  // RNE, finite inputs only
  return r >> 16;
}

// fp32 N(0,1): exponent field in [~90,130] (or 0); packed-bf16 read as u32 -> ~200+.
__device__ __forceinline__ bool sniff_fp32(const void* p) {
  const uint32_t* w = (const uint32_t*)p;
  bool ok = true;
  #pragma unroll 1
  for (int i = 0; i < 64; ++i) {
    uint32_t e = (w[i] >> 23) & 0xFFu;
    if (!(e == 0u || (e >= 64u && e <= 192u))) ok = false;
  }
  return ok;
}

__device__ __forceinline__ short8 cvt8(const void* src, bool fp32) {
  short8 d;
  if (fp32) {
    const float* s = (const float*)src;
    f32x4 a = *(const f32x4*)s, c = *(const f32x4*)(s + 4);
    #pragma unroll
    for (int j = 0; j < 4; ++j) { d[j] = (short)f2bf(a[j]); d[4 + j] = (short)f2bf(c[j]); }
  } else {
    d = *(const short8*)src;
  }
  return d;
}

// ---------- K (any dtype) -> bf16, same layout (streaming) ----------
__global__ void kbf_kernel(const void* __restrict__ in, uint16_t* __restrict__ out) {
  bool fp32 = sniff_fp32(in);
  size_t i = ((size_t)blockIdx.x * 256 + threadIdx.x) * 8;
  const void* src = fp32 ? (const void*)((const float*)in + i)
                         : (const void*)((const uint16_t*)in + i);
  *(short8*)(out + i) = cvt8(src, fp32);
}

// ---------- V [b][key][dv] -> V^T [b][dv][key] bf16: direct gather, L1-reuse ----------
__global__ void vt_kernel(const void* __restrict__ V, uint16_t* __restrict__ vt) {
  bool fp32 = sniff_fp32(V);
  int kt = blockIdx.x, dt = blockIdx.y, b = blockIdx.z;
  int t  = threadIdx.x;            // 512 threads
  int dv = t >> 3;                 // 0..63
  int kg = t & 7;                  // key octet
  int dvg = dt * 64 + dv;
  size_t base = (size_t)b * S_ * D_;
  short8 o;
  #pragma unroll
  for (int j = 0; j < 8; ++j) {
    size_t off = base + (size_t)(kt * 64 + kg * 8 + j) * D_ + dvg;
    if (fp32) o[j] = (short)f2bf(((const float*)V)[off]);
    else      o[j] = (short)((const uint16_t*)V)[off];
  }
  *(short8*)(vt + ((size_t)b * D_ + dvg) * S_ + kt * 64 + kg * 8) = o;
}

// ---------- FAST staging (bf16 ws buffers via global_load_lds, width 16) ----------
__device__ __forceinline__ void stage_K(char* smem, const uint16_t* kg, int w, int lane, int kt) {
  #pragma unroll
  for (int p = 0; p < 8; ++p) {
    int n = p * 4 + w;                               // key row 0..31
    int g = (lane & ~7) | ((lane ^ n) & 7);          // slot s holds chunk (s&~7)|((s^n)&7)
    gl_lds16(kg + ((size_t)(kt * KTL + n)) * D_ + g * 8, smem + OFF_K + (p * 4 + w) * 1024);
  }
}
__device__ __forceinline__ void stage_VT(char* smem, const uint16_t* vtg, int w, int lane, int kt) {
  #pragma unroll
  for (int p = 0; p < 8; ++p) {
    int dvl = p * 16 + (lane >> 2);                  // wave-local dv row 0..127
    int g = (lane & 3) ^ (dvl & 3);                  // slot s holds chunk s^(dvl&3)
    gl_lds16(vtg + ((size_t)(w * 128 + dvl)) * S_ + kt * KTL + g * 8,
             smem + OFF_V + w * 8192 + p * 1024);
  }
}
// ---------- SLOW staging (convert through registers) ----------
__device__ __forceinline__ void stage_K_slow(char* smem, const void* kg, bool fp32,
                                             int w, int lane, int kt) {
  #pragma unroll
  for (int p = 0; p < 8; ++p) {
    int n = p * 4 + w;
    size_t off = ((size_t)(kt * KTL + n)) * D_ + lane * 8;
    const void* src = fp32 ? (const void*)((const float*)kg + off)
                           : (const void*)((const uint16_t*)kg + off);
    short8 d = cvt8(src, fp32);
    int s = (lane & ~7) | ((lane ^ n) & 7);
    *(short8*)(smem + OFF_K + n * 1024 + s * 16) = d;
  }
}
__device__ __forceinline__ void stage_V_slow(char* smem, const void* vg, bool fp32,
                                             int w, int lane, int kt) {
  #pragma unroll
  for (int p = 0; p < 8; ++p) {
    int n = p * 4 + w;
    size_t off = ((size_t)(kt * KTL + n)) * D_ + lane * 8;
    const void* src = fp32 ? (const void*)((const float*)vg + off)
                           : (const void*)((const uint16_t*)vg + off);
    short8 d = cvt8(src, fp32);
    *(short8*)(smem + OFF_V + n * 1024 + lane * 16) = d;   // natural layout
  }
}

// ---------- flash attention: 32-query tile, 4 waves, 2 blocks/CU ----------
template<bool FAST>
__global__ __launch_bounds__(256, 2)
void attn_kernel(const void* __restrict__ Q, const void* __restrict__ K,
                 const void* __restrict__ V, const void* __restrict__ mask,
                 const uint16_t* __restrict__ kbf, const uint16_t* __restrict__ vtbf,
                 void* __restrict__ out) {
  extern __shared__ char smem[];
  const int tid  = threadIdx.x;
  const int lane = tid & 63;
  const int w    = tid >> 6;
  const int m15  = lane & 15;
  const int kq   = lane >> 4;

  const bool fp32 = sniff_fp32(Q);

  const int b     = blockIdx.x;        // batch; linear%8 == XCD -> per-batch L2 residency
  const int qbase = blockIdx.y * QT;
  const int rt_qk = w >> 1;            // QK^T tile row (q half)
  const int cb_qk = (w & 1) * 16;      // QK^T tile col (key half)

  const uint16_t* kgf  = FAST ? (kbf + (size_t)b * S_ * D_) : nullptr;
  const uint16_t* vtgf = FAST ? (vtbf + (size_t)b * D_ * S_) : nullptr;
  const void* kgs = fp32 ? (const void*)((const float*)K + (size_t)b * S_ * D_)
                         : (const void*)((const uint16_t*)K + (size_t)b * S_ * D_);
  const void* vgs = fp32 ? (const void*)((const float*)V + (size_t)b * S_ * D_)
                         : (const void*)((const uint16_t*)V + (size_t)b * S_ * D_);

  // ---- pack this batch's key mask into 64 LDS words (dtype auto-detect) ----
  if (tid < 64) {
    const uint32_t* mw = (const uint32_t*)mask;
    const uint8_t*  mb = (const uint8_t*)mask;
    bool is64 = true, any_even = false, is32 = true;
    for (int j = 0; j < 64; ++j) {
      uint32_t lo = mw[2 * j], hi = mw[2 * j + 1];
      if (hi != 0u || lo > 1u) is64 = false;
      if (lo) any_even = true;
    }
    is64 = is64 && any_even;
    for (int j = 0; j < 128; ++j) {
      uint32_t x = mw[j];
      if (x != 0u && x != 1u && x != 0x3F800000u) is32 = false;
    }
    uint32_t bits = 0;
    int base = b * S_ + tid * 32;
    for (int e = 0; e < 32; ++e) {
      uint32_t x = is64 ? mw[2 * (base + e)]
                        : (is32 ? mw[base + e] : (uint32_t)mb[base + e]);
      bits |= (x ? 1u : 0u) << e;
    }
    *(uint32_t*)(smem + OFF_M + tid * 4) = bits;
  }

  // ---- Q fragments resident in registers (A-layout = row-major) ----
  short8 aq[16];
  {
    size_t q0 = ((size_t)b * S_ + qbase + rt_qk * 16 + m15) * D_ + kq * 8;
    #pragma unroll
    for (int sl = 0; sl < 16; ++sl) {
      size_t off = q0 + sl * 32;
      const void* src = fp32 ? (const void*)((const float*)Q + off)
                             : (const void*)((const uint16_t*)Q + off);
      aq[sl] = cvt8(src, fp32);
    }
  }

  f32x4 acc_o[2][8];                   // wave dv slice [w*128, w*128+128)
  #pragma unroll
  for (int i = 0; i < 2; ++i)
    #pragma unroll
    for (int j = 0; j < 8; ++j)
      acc_o[i][j] = (f32x4){0.f, 0.f, 0.f, 0.f};

  float m_run = -1e30f, l_run = 0.f;
  const float k1 = 0.06375872f;        // log2(e)/sqrt(512); exp2-domain softmax

  if (FAST) { stage_K(smem, kgf, w, lane, 0); stage_VT(smem, vtgf, w, lane, 0); }

  for (int kt = 0; kt < NIT; ++kt) {
    if (!FAST) {
      __syncthreads();                 // prior-iter LDS reads drained before overwrite
      stage_K_slow(smem, kgs, fp32, w, lane, kt);
      stage_V_slow(smem, vgs, fp32, w, lane, kt);
    }
    __syncthreads();                   // B1: staged tiles visible (barrier drains vmcnt)

    int keyg = kt * KTL + cb_qk + m15;
    float bv = ((*(const uint32_t*)(smem + OFF_M + (keyg >> 5) * 4) >> (keyg & 31)) & 1u)
               ? -3.0e38f : 0.f;

    // ---- QK^T: one 16x16 tile per wave; Q regs, K B-frags from LDS ----
    f32x4 acc_s = (f32x4){0.f, 0.f, 0.f, 0.f};
    #pragma unroll
    for (int sl = 0; sl < 16; ++sl) {
      int n  = cb_qk + m15;
      int c  = sl * 4 + kq;
      int cs = (c & ~7) | ((c ^ n) & 7);
      short8 bf = *(const short8*)(smem + OFF_K + n * 1024 + cs * 16);
      acc_s = __builtin_amdgcn_mfma_f32_16x16x32_bf16(aq[sl], bf, acc_s, 0, 0, 0);
    }

    // ---- S^T fp32 (exp2-domain, bias folded), xblk-swizzled ----
    {
      int key  = cb_qk + m15;
      int blk  = rt_qk * 4 + kq;
      int xblk = blk ^ (key & 7);
      f32x4 sv;
      #pragma unroll
      for (int r = 0; r < 4; ++r) sv[r] = acc_s[r] * k1 + bv;
      *(f32x4*)(smem + OFF_ST + key * 128 + xblk * 16) = sv;
    }
    __syncthreads();                   // B2: S^T visible; all K reads drained

    if (FAST && kt < NIT - 1) stage_K(smem, kgf, w, lane, kt + 1);  // overlaps softmax+PV

    // ---- online softmax: row r = w*8+(lane>>3); 8-lane group over 32 keys ----
    {
      int r  = w * 8 + (lane >> 3);
      int k0 = (lane & 7) * 4;
      float u[4];
      #pragma unroll
      for (int i = 0; i < 4; ++i) {
        int k    = k0 + i;
        int xblk = (r >> 2) ^ (k & 7);
        u[i] = *(const float*)(smem + OFF_ST + k * 128 + xblk * 16 + (r & 3) * 4);
      }
      float mt = fmaxf(fmaxf(u[0], u[1]), fmaxf(u[2], u[3]));
      mt = fmaxf(mt, __shfl_xor(mt, 1, 64));
      mt = fmaxf(mt, __shfl_xor(mt, 2, 64));
      mt = fmaxf(mt, __shfl_xor(mt, 4, 64));
      float m_new = fmaxf(m_run, mt);
      float alpha = exp2f(m_run - m_new);
      float s = 0.f;
      #pragma unroll
      for (int i = 0; i < 4; ++i) { u[i] = exp2f(u[i] - m_new); s += u[i]; }
      s += __shfl_xor(s, 1, 64);
      s += __shfl_xor(s, 2, 64);
      s += __shfl_xor(s, 4, 64);
      l_run = l_run * alpha + s;
      m_run = m_new;
      uint2 d;
      d.x = f2bf(u[0]) | (f2bf(u[1]) << 16);
      d.y = f2bf(u[2]) | (f2bf(u[3]) << 16);
      *(uint2*)(smem + OFF_P + r * 64 + k0 * 2) = d;
      if ((lane & 7) == 0) {
        *(float*)(smem + OFF_A + r * 4) = alpha;
        *(float*)(smem + OFF_L + r * 4) = l_run;
      }
    }
    __syncthreads();                   // B3: P/alpha/l visible

    // ---- PV: rescale acc, O += P·V over this 32-key slab ----
    #pragma unroll
    for (int rt = 0; rt < 2; ++rt) {
      f32x4 al = *(const f32x4*)(smem + OFF_A + (rt * 16 + kq * 4) * 4);
      #pragma unroll
      for (int ct = 0; ct < 8; ++ct) acc_o[rt][ct] *= al;
    }
    short8 ap[2];
    #pragma unroll
    for (int rt = 0; rt < 2; ++rt)
      ap[rt] = *(const short8*)(smem + OFF_P + (rt * 16 + m15) * 64 + kq * 16);
    #pragma unroll
    for (int ct = 0; ct < 8; ++ct) {
      short8 bvv;
      if (FAST) {
        int dvL = ct * 16 + m15;                       // wave-local dv 0..127
        int cs  = kq ^ (dvL & 3);
        bvv = *(const short8*)(smem + OFF_V + w * 8192 + dvL * 64 + cs * 16);
      } else {
        #pragma unroll
        for (int j = 0; j < 8; ++j)
          bvv[j] = *(const short*)(smem + OFF_V + (kq * 8 + j) * 1024
                                   + (w * 128 + ct * 16 + m15) * 2);
      }
      #pragma unroll
      for (int rt = 0; rt < 2; ++rt)
        acc_o[rt][ct] = __builtin_amdgcn_mfma_f32_16x16x32_bf16(
            ap[rt], bvv, acc_o[rt][ct], 0, 0, 0);
    }

    if (FAST && kt < NIT - 1) stage_VT(smem, vtgf, w, lane, kt + 1); // wave-private region
  }

  // ---- epilogue: O /= l (guarded), store in input dtype ----
  #pragma unroll
  for (int rt = 0; rt < 2; ++rt) {
    f32x4 lv = *(const f32x4*)(smem + OFF_L + (rt * 16 + kq * 4) * 4);
    f32x4 inv;
    #pragma unroll
    for (int r = 0; r < 4; ++r) inv[r] = lv[r] > 0.f ? 1.f / lv[r] : 0.f;
    #pragma unroll
    for (int ct = 0; ct < 8; ++ct) {
      int col = w * 128 + ct * 16 + m15;
      #pragma unroll
      for (int r = 0; r < 4; ++r) {
        int row = qbase + rt * 16 + kq * 4 + r;
        size_t idx = ((size_t)b * S_ + row) * D_ + col;
        float val = acc_o[rt][ct][r] * inv[r];
        if (fp32) ((float*)out)[idx] = val;
        else      ((uint16_t*)out)[idx] = (uint16_t)f2bf(val);
      }
    }
  }
}

extern "C" void kernel_launch(void* const* d_in, const int* in_sizes, int n_in,
                              void* d_out, int out_size, void* d_ws, size_t ws_size,
                              hipStream_t stream) {
  (void)in_sizes; (void)n_in; (void)out_size;
  const void* Q    = d_in[0];
  const void* K    = d_in[1];
  const void* V    = d_in[2];
  const void* mask = d_in[3];

  const size_t half = (size_t)B_ * S_ * D_ * 2;     // 16 MiB per bf16 buffer
  bool fast = ws_size >= 2 * half;

  if (fast) {
    uint16_t* kbf  = (uint16_t*)d_ws;
    uint16_t* vtbf = (uint16_t*)((char*)d_ws + half);
    kbf_kernel<<<4096, 256, 0, stream>>>(K, kbf);
    vt_kernel<<<dim3(32, 8, 8), 512, 0, stream>>>(V, vtbf);
    hipFuncSetAttribute((const void*)attn_kernel<true>,
                        hipFuncAttributeMaxDynamicSharedMemorySize, LDS_BYTES);
    attn_kernel<true><<<dim3(8, S_ / QT), 256, LDS_BYTES, stream>>>(
        Q, K, V, mask, kbf, vtbf, d_out);
  } else {
    hipFuncSetAttribute((const void*)attn_kernel<false>,
                        hipFuncAttributeMaxDynamicSharedMemorySize, LDS_BYTES);
    attn_kernel<false><<<dim3(8, S_ / QT), 256, LDS_BYTES, stream>>>(
        Q, K, V, mask, nullptr, nullptr, d_out);
  }
}

// Round 5
// 298.773 us; speedup vs baseline: 1.1701x; 1.1329x over previous
//
#include <hip/hip_runtime.h>
#include <stdint.h>
#include <stddef.h>

#define B_ 8
#define S_ 2048
#define D_ 512
#define QT 64            // q rows per block
#define KTL 32           // keys per iter
#define NIT (S_ / KTL)   // 64

typedef __attribute__((ext_vector_type(8))) short short8;   // 8 x bf16 MFMA frag
typedef __attribute__((ext_vector_type(4))) float f32x4;    // MFMA accum

// ---- LDS layout (bytes), 78592 total; one 8-wave block per CU ----
#define OFF_K0  0         // K tile buf0: 32 keys x 1024B bf16, chunk-swizzled
#define OFF_K1  32768     // FAST: K tile buf1 (double buffer); SLOW: V natural [32 key][1024B]
#define OFF_ST  65536     // S^T fp32 [32 key][256B = 16 chunks], xblk-swizzled
#define OFF_P   73728     // P bf16 [64 q][64B]
#define OFF_A   77824     // 64 f32 alpha
#define OFF_L   78080     // 64 f32 l
#define OFF_M   78336     // 64 u32 packed mask bits for this batch
#define LDS_BYTES 78592

__device__ __forceinline__ void gl_lds16(const void* g, void* l) {
  __builtin_amdgcn_global_load_lds(
      (const __attribute__((address_space(1))) uint32_t*)g,
      (__attribute__((address_space(3))) uint32_t*)l, 16, 0, 0);
}

// CK-style cheap barrier: order LDS only, leave vmem (DMA/prefetch) in flight.
__device__ __forceinline__ void bar_lgkm() {
  __asm__ __volatile__("" ::: "memory");
  __builtin_amdgcn_s_waitcnt(0xC07F);          // lgkmcnt(0), vmcnt(63), expcnt(7)
  __builtin_amdgcn_s_barrier();
  __asm__ __volatile__("" ::: "memory");
}
// Iter-top barrier: also drain vmem (the only outstanding vmem here is the
// K-DMA issued a full iteration ago -> near-zero actual wait).
__device__ __forceinline__ void bar_vm0() {
  __asm__ __volatile__("" ::: "memory");
  __builtin_amdgcn_s_waitcnt(0x0070);          // vmcnt(0), lgkmcnt(0), expcnt(7)
  __builtin_amdgcn_s_barrier();
  __asm__ __volatile__("" ::: "memory");
}

__device__ __forceinline__ uint32_t f2bf(float f) {
  union { float f; uint32_t u; } x; x.f = f;
  uint32_t r = x.u + 0x7FFFu + ((x.u >> 16) & 1u);  // RNE, finite inputs only
  return r >> 16;
}

// fp32 N(0,1): exponent field in [~90,130] (or 0); packed-bf16 read as u32 -> ~200+.
__device__ __forceinline__ bool sniff_fp32(const void* p) {
  const uint32_t* w = (const uint32_t*)p;
  bool ok = true;
  #pragma unroll 1
  for (int i = 0; i < 64; ++i) {
    uint32_t e = (w[i] >> 23) & 0xFFu;
    if (!(e == 0u || (e >= 64u && e <= 192u))) ok = false;
  }
  return ok;
}

__device__ __forceinline__ short8 cvt8(const void* src, bool fp32) {
  short8 d;
  if (fp32) {
    const float* s = (const float*)src;
    f32x4 a = *(const f32x4*)s, c = *(const f32x4*)(s + 4);
    #pragma unroll
    for (int j = 0; j < 4; ++j) { d[j] = (short)f2bf(a[j]); d[4 + j] = (short)f2bf(c[j]); }
  } else {
    d = *(const short8*)src;
  }
  return d;
}

// ---------- merged prep: K -> bf16 (same layout) + V -> V^T bf16 ----------
// grid (32 keytiles-of-64, 8 dvtiles-of-64, 8 batch), 512 threads
__global__ void prep_kernel(const void* __restrict__ K, const void* __restrict__ V,
                            uint16_t* __restrict__ kbf, uint16_t* __restrict__ vt) {
  bool fp32 = sniff_fp32(K);
  int kt = blockIdx.x, dt = blockIdx.y, b = blockIdx.z;
  int t  = threadIdx.x;
  // K convert: rows kt*64 + (t>>3), cols dt*64 + (t&7)*8 .. +8   (coalesced)
  {
    size_t off = (size_t)b * S_ * D_ + (size_t)(kt * 64 + (t >> 3)) * D_ + dt * 64 + (t & 7) * 8;
    const void* src = fp32 ? (const void*)((const float*)K + off)
                           : (const void*)((const uint16_t*)K + off);
    *(short8*)(kbf + off) = cvt8(src, fp32);
  }
  // V transpose: thread t -> dv = t>>3, key octet kg = t&7
  {
    int dvg = dt * 64 + (t >> 3);
    int kg  = t & 7;
    size_t base = (size_t)b * S_ * D_;
    short8 o;
    #pragma unroll
    for (int j = 0; j < 8; ++j) {
      size_t off = base + (size_t)(kt * 64 + kg * 8 + j) * D_ + dvg;
      if (fp32) o[j] = (short)f2bf(((const float*)V)[off]);
      else      o[j] = (short)((const uint16_t*)V)[off];
    }
    *(short8*)(vt + ((size_t)b * D_ + dvg) * S_ + kt * 64 + kg * 8) = o;
  }
}

// ---------- FAST K staging: 8 waves x 4 rows, global_load_lds width 16 ----------
__device__ __forceinline__ void stage_K(char* buf, const uint16_t* kg, int w, int lane, int kt) {
  #pragma unroll
  for (int p = 0; p < 4; ++p) {
    int n = p * 8 + w;                               // key row 0..31
    int g = (lane & ~7) | ((lane ^ n) & 7);          // slot s holds chunk (s&~7)|((s^n)&7)
    gl_lds16(kg + ((size_t)(kt * KTL + n)) * D_ + g * 8, buf + n * 1024);
  }
}
// ---------- SLOW staging (convert through registers) ----------
__device__ __forceinline__ void stage_K_slow(char* buf, const void* kg, bool fp32,
                                             int w, int lane, int kt) {
  #pragma unroll
  for (int p = 0; p < 4; ++p) {
    int n = p * 8 + w;
    size_t off = ((size_t)(kt * KTL + n)) * D_ + lane * 8;
    const void* src = fp32 ? (const void*)((const float*)kg + off)
                           : (const void*)((const uint16_t*)kg + off);
    short8 d = cvt8(src, fp32);
    int s = (lane & ~7) | ((lane ^ n) & 7);
    *(short8*)(buf + n * 1024 + s * 16) = d;
  }
}
__device__ __forceinline__ void stage_V_slow(char* smem, const void* vg, bool fp32,
                                             int w, int lane, int kt) {
  #pragma unroll
  for (int p = 0; p < 4; ++p) {
    int n = p * 8 + w;
    size_t off = ((size_t)(kt * KTL + n)) * D_ + lane * 8;
    const void* src = fp32 ? (const void*)((const float*)vg + off)
                           : (const void*)((const uint16_t*)vg + off);
    short8 d = cvt8(src, fp32);
    *(short8*)(smem + OFF_K1 + n * 1024 + lane * 16) = d;   // natural layout
  }
}

// ---------- flash attention: 64-q tile, 8 waves, 1 block/CU ----------
template<bool FAST>
__global__ __launch_bounds__(512, 2)
void attn_kernel(const void* __restrict__ Q, const void* __restrict__ K,
                 const void* __restrict__ V, const void* __restrict__ mask,
                 const uint16_t* __restrict__ kbf, const uint16_t* __restrict__ vtbf,
                 void* __restrict__ out) {
  extern __shared__ char smem[];
  const int tid  = threadIdx.x;
  const int lane = tid & 63;
  const int w    = tid >> 6;          // wave 0..7
  const int m15  = lane & 15;
  const int kq   = lane >> 4;

  const bool fp32 = sniff_fp32(Q);

  const int b     = blockIdx.x;       // batch; linear%8 == XCD -> per-batch L2 residency
  const int qbase = blockIdx.y * QT;
  const int qt_w  = w >> 1;           // QK q-tile 0..3 (16 rows)
  const int kh    = w & 1;            // QK key half

  const uint16_t* kgf  = FAST ? (kbf + (size_t)b * S_ * D_) : nullptr;
  const uint16_t* vtg  = FAST ? (vtbf + (size_t)b * D_ * S_) : nullptr;
  const void* kgs = fp32 ? (const void*)((const float*)K + (size_t)b * S_ * D_)
                         : (const void*)((const uint16_t*)K + (size_t)b * S_ * D_);
  const void* vgs = fp32 ? (const void*)((const float*)V + (size_t)b * S_ * D_)
                         : (const void*)((const uint16_t*)V + (size_t)b * S_ * D_);

  // ---- pack this batch's key mask into 64 LDS words (dtype auto-detect) ----
  if (tid < 64) {
    const uint32_t* mw = (const uint32_t*)mask;
    const uint8_t*  mb = (const uint8_t*)mask;
    bool is64 = true, any_even = false, is32 = true;
    for (int j = 0; j < 64; ++j) {
      uint32_t lo = mw[2 * j], hi = mw[2 * j + 1];
      if (hi != 0u || lo > 1u) is64 = false;
      if (lo) any_even = true;
    }
    is64 = is64 && any_even;
    for (int j = 0; j < 128; ++j) {
      uint32_t x = mw[j];
      if (x != 0u && x != 1u && x != 0x3F800000u) is32 = false;
    }
    uint32_t bits = 0;
    int base = b * S_ + tid * 32;
    for (int e = 0; e < 32; ++e) {
      uint32_t x = is64 ? mw[2 * (base + e)]
                        : (is32 ? mw[base + e] : (uint32_t)mb[base + e]);
      bits |= (x ? 1u : 0u) << e;
    }
    *(uint32_t*)(smem + OFF_M + tid * 4) = bits;
  }

  // ---- Q fragments resident in registers (A-layout = row-major) ----
  short8 aq[16];
  {
    size_t q0 = ((size_t)b * S_ + qbase + qt_w * 16 + m15) * D_ + kq * 8;
    #pragma unroll
    for (int sl = 0; sl < 16; ++sl) {
      size_t off = q0 + sl * 32;
      const void* src = fp32 ? (const void*)((const float*)Q + off)
                             : (const void*)((const uint16_t*)Q + off);
      aq[sl] = cvt8(src, fp32);
    }
  }

  f32x4 acc_o[4][4];                  // 64 q rows x wave dv slice [w*64, w*64+64)
  #pragma unroll
  for (int i = 0; i < 4; ++i)
    #pragma unroll
    for (int j = 0; j < 4; ++j)
      acc_o[i][j] = (f32x4){0.f, 0.f, 0.f, 0.f};

  float m_run = -1e30f, l_run = 0.f;
  const float k1 = 0.06375872f;       // log2(e)/sqrt(512); exp2-domain softmax

  if (FAST) stage_K(smem + OFF_K0, kgf, w, lane, 0);

  for (int kt = 0; kt < NIT; ++kt) {
    char* kbuf = smem + ((kt & 1) && FAST ? OFF_K1 : OFF_K0);
    if (FAST) {
      bar_vm0();                      // B1: K[kt] DMA (issued 1 iter ago) landed
    } else {
      __syncthreads();                // readers of previous tiles done
      stage_K_slow(smem + OFF_K0, kgs, fp32, w, lane, kt);
      stage_V_slow(smem, vgs, fp32, w, lane, kt);
      __syncthreads();
    }

    // V fragments for THIS iter: direct global -> regs (no LDS, no reuse lost)
    short8 vf[4];
    if (FAST) {
      #pragma unroll
      for (int ct = 0; ct < 4; ++ct)
        vf[ct] = *(const short8*)(vtg + (size_t)(w * 64 + ct * 16 + m15) * S_
                                  + kt * KTL + kq * 8);
      if (kt < NIT - 1)               // prefetch next K tile into other buffer
        stage_K(smem + ((kt & 1) ? OFF_K0 : OFF_K1), kgf, w, lane, kt + 1);
    }

    int keyg = kt * KTL + kh * 16 + m15;
    float bv = ((*(const uint32_t*)(smem + OFF_M + (keyg >> 5) * 4) >> (keyg & 31)) & 1u)
               ? -3.0e38f : 0.f;

    // ---- QK^T: wave does 16q x 16k tile; Q regs, K B-frags from LDS ----
    f32x4 acc_s = (f32x4){0.f, 0.f, 0.f, 0.f};
    #pragma unroll
    for (int sl = 0; sl < 16; ++sl) {
      int n  = kh * 16 + m15;
      int c  = sl * 4 + kq;
      int cs = (c & ~7) | ((c ^ n) & 7);
      short8 bf = *(const short8*)(kbuf + n * 1024 + cs * 16);
      acc_s = __builtin_amdgcn_mfma_f32_16x16x32_bf16(aq[sl], bf, acc_s, 0, 0, 0);
    }

    // ---- S^T fp32 (exp2-domain, bias folded); xblk has key bits 0..4 ----
    {
      int key  = kh * 16 + m15;
      int blk  = qt_w * 4 + kq;                       // q>>2
      int xblk = blk ^ (key & 15) ^ ((key >> 2) & 3);
      f32x4 sv;
      #pragma unroll
      for (int r = 0; r < 4; ++r) sv[r] = acc_s[r] * k1 + bv;
      *(f32x4*)(smem + OFF_ST + key * 256 + xblk * 16) = sv;
    }
    bar_lgkm();                        // B2: S^T visible (LDS-only wait)

    // ---- online softmax: row r = w*8+(lane>>3); 8 lanes cover 32 keys ----
    {
      int r  = w * 8 + (lane >> 3);
      int k0 = (lane & 7) * 4;
      float u[4];
      #pragma unroll
      for (int i = 0; i < 4; ++i) {
        int k    = k0 + i;
        int xblk = (r >> 2) ^ (k & 15) ^ ((k >> 2) & 3);
        u[i] = *(const float*)(smem + OFF_ST + k * 256 + xblk * 16 + (r & 3) * 4);
      }
      float mt = fmaxf(fmaxf(u[0], u[1]), fmaxf(u[2], u[3]));
      mt = fmaxf(mt, __shfl_xor(mt, 1, 64));
      mt = fmaxf(mt, __shfl_xor(mt, 2, 64));
      mt = fmaxf(mt, __shfl_xor(mt, 4, 64));
      float m_new = fmaxf(m_run, mt);
      float alpha = exp2f(m_run - m_new);
      float s = 0.f;
      #pragma unroll
      for (int i = 0; i < 4; ++i) { u[i] = exp2f(u[i] - m_new); s += u[i]; }
      s += __shfl_xor(s, 1, 64);
      s += __shfl_xor(s, 2, 64);
      s += __shfl_xor(s, 4, 64);
      l_run = l_run * alpha + s;
      m_run = m_new;
      uint2 d;
      d.x = f2bf(u[0]) | (f2bf(u[1]) << 16);
      d.y = f2bf(u[2]) | (f2bf(u[3]) << 16);
      *(uint2*)(smem + OFF_P + r * 64 + k0 * 2) = d;
      if ((lane & 7) == 0) {
        *(float*)(smem + OFF_A + r * 4) = alpha;
        *(float*)(smem + OFF_L + r * 4) = l_run;
      }
    }
    bar_lgkm();                        // B3: P/alpha/l visible (LDS-only wait)

    // ---- PV: all 64 q rows x wave's 64-dv slice ----
    #pragma unroll
    for (int rt = 0; rt < 4; ++rt) {
      f32x4 al = *(const f32x4*)(smem + OFF_A + (rt * 16 + kq * 4) * 4);
      #pragma unroll
      for (int ct = 0; ct < 4; ++ct) acc_o[rt][ct] *= al;
    }
    short8 ap[4];
    #pragma unroll
    for (int rt = 0; rt < 4; ++rt)
      ap[rt] = *(const short8*)(smem + OFF_P + (rt * 16 + m15) * 64 + kq * 16);
    #pragma unroll
    for (int ct = 0; ct < 4; ++ct) {
      short8 bvv;
      if (FAST) {
        bvv = vf[ct];
      } else {
        #pragma unroll
        for (int j = 0; j < 8; ++j)
          bvv[j] = *(const short*)(smem + OFF_K1 + (kq * 8 + j) * 1024
                                   + (w * 64 + ct * 16 + m15) * 2);
      }
      #pragma unroll
      for (int rt = 0; rt < 4; ++rt)
        acc_o[rt][ct] = __builtin_amdgcn_mfma_f32_16x16x32_bf16(
            ap[rt], bvv, acc_o[rt][ct], 0, 0, 0);
    }
  }

  // ---- epilogue: O /= l (guarded), store in input dtype ----
  #pragma unroll
  for (int rt = 0; rt < 4; ++rt) {
    f32x4 lv = *(const f32x4*)(smem + OFF_L + (rt * 16 + kq * 4) * 4);
    f32x4 inv;
    #pragma unroll
    for (int r = 0; r < 4; ++r) inv[r] = lv[r] > 0.f ? 1.f / lv[r] : 0.f;
    #pragma unroll
    for (int ct = 0; ct < 4; ++ct) {
      int col = w * 64 + ct * 16 + m15;
      #pragma unroll
      for (int r = 0; r < 4; ++r) {
        int row = qbase + rt * 16 + kq * 4 + r;
        size_t idx = ((size_t)b * S_ + row) * D_ + col;
        float val = acc_o[rt][ct][r] * inv[r];
        if (fp32) ((float*)out)[idx] = val;
        else      ((uint16_t*)out)[idx] = (uint16_t)f2bf(val);
      }
    }
  }
}

extern "C" void kernel_launch(void* const* d_in, const int* in_sizes, int n_in,
                              void* d_out, int out_size, void* d_ws, size_t ws_size,
                              hipStream_t stream) {
  (void)in_sizes; (void)n_in; (void)out_size;
  const void* Q    = d_in[0];
  const void* K    = d_in[1];
  const void* V    = d_in[2];
  const void* mask = d_in[3];

  const size_t half = (size_t)B_ * S_ * D_ * 2;     // 16 MiB per bf16 buffer
  bool fast = ws_size >= 2 * half;

  if (fast) {
    uint16_t* kbf  = (uint16_t*)d_ws;
    uint16_t* vtbf = (uint16_t*)((char*)d_ws + half);
    prep_kernel<<<dim3(32, 8, 8), 512, 0, stream>>>(K, V, kbf, vtbf);
    hipFuncSetAttribute((const void*)attn_kernel<true>,
                        hipFuncAttributeMaxDynamicSharedMemorySize, LDS_BYTES);
    attn_kernel<true><<<dim3(8, S_ / QT), 512, LDS_BYTES, stream>>>(
        Q, K, V, mask, kbf, vtbf, d_out);
  } else {
    hipFuncSetAttribute((const void*)attn_kernel<false>,
                        hipFuncAttributeMaxDynamicSharedMemorySize, LDS_BYTES);
    attn_kernel<false><<<dim3(8, S_ / QT), 512, LDS_BYTES, stream>>>(
        Q, K, V, mask, nullptr, nullptr, d_out);
  }
}